// Round 9
// baseline (273.240 us; speedup 1.0000x reference)
//
#include <hip/hip_runtime.h>
#include <hip/hip_bf16.h>

#define BB 4
#define TT 2048
#define CC 1024
#define HH 16
#define DD 64

typedef __bf16 bf16x8 __attribute__((ext_vector_type(8)));
typedef float f32x4 __attribute__((ext_vector_type(4)));
typedef unsigned int u32x4 __attribute__((ext_vector_type(4)));
typedef unsigned int u32x2 __attribute__((ext_vector_type(2)));
typedef unsigned short u16x8 __attribute__((ext_vector_type(8)));
typedef unsigned short u16x4 __attribute__((ext_vector_type(4)));
typedef unsigned int u32;

__device__ __forceinline__ unsigned short f2bf(float f) {
  u32 u = __builtin_bit_cast(u32, f);
  u += 0x7fff + ((u >> 16) & 1);   // RNE
  return (unsigned short)(u >> 16);
}

// bare v_exp_f32: skips the IEEE-denormal fixup sequence hipcc emits for
// exp2f. Inputs are normal scores or -3e38 (exp->0). 1 VALU.
__device__ __forceinline__ float exp2_raw(float x) {
  float r;
  asm("v_exp_f32 %0, %1" : "=v"(r) : "v"(x));
  return r;
}

__device__ __forceinline__ bf16x8 lds_load8(const unsigned short* p) {
  u32x4 t = *(const u32x4*)p;
  return __builtin_bit_cast(bf16x8, t);
}

// async 16B global->LDS (dest = wave-uniform base + lane*16)
__device__ __forceinline__ void g2l16(const unsigned short* g, unsigned short* l) {
  __builtin_amdgcn_global_load_lds(
      (const __attribute__((address_space(1))) u32*)g,
      (__attribute__((address_space(3))) u32*)l, 16, 0, 0);
}

// ---------------- fused prep: xcast + W_attn^T + W_proj^T ----------------
__global__ __launch_bounds__(256) void prep(
    const float* __restrict__ x, const float* __restrict__ Wa,
    const float* __restrict__ Wp, unsigned short* __restrict__ xb,
    unsigned short* __restrict__ Wta, unsigned short* __restrict__ Wtp)
{
  __shared__ unsigned short T[64 * 68];
  const int tid = threadIdx.x;
  const int bid = blockIdx.x;
  if (bid < 4096) {                       // x fp32 -> bf16
    int i = (bid * 256 + tid) * 8;
    f32x4 a = *(const f32x4*)(x + i);
    f32x4 b = *(const f32x4*)(x + i + 4);
    u16x8 o;
    o[0] = f2bf(a[0]); o[1] = f2bf(a[1]); o[2] = f2bf(a[2]); o[3] = f2bf(a[3]);
    o[4] = f2bf(b[0]); o[5] = f2bf(b[1]); o[6] = f2bf(b[2]); o[7] = f2bf(b[3]);
    *(u16x8*)(xb + i) = o;
    return;
  }
  const float* W; unsigned short* Wt; int N, n0, k0;
  if (bid < 4096 + 768) {
    int b2 = bid - 4096;  W = Wa; Wt = Wta; N = 3072;
    n0 = (b2 % 48) * 64;  k0 = (b2 / 48) * 64;
  } else {
    int b2 = bid - 4864;  W = Wp; Wt = Wtp; N = 1024;
    n0 = (b2 % 16) * 64;  k0 = (b2 / 16) * 64;
  }
#pragma unroll
  for (int it = 0; it < 4; ++it) {
    int idx = it * 256 + tid;
    int kk = idx >> 4, nn = (idx & 15) * 4;
    f32x4 v = *(const f32x4*)(W + (size_t)(k0 + kk) * N + n0 + nn);
    u16x4 p;
    p[0] = f2bf(v[0]); p[1] = f2bf(v[1]); p[2] = f2bf(v[2]); p[3] = f2bf(v[3]);
    *(u16x4*)(&T[kk * 68 + nn]) = p;
  }
  __syncthreads();
#pragma unroll
  for (int it = 0; it < 4; ++it) {
    int idx = it * 256 + tid;
    int nn = idx >> 4, kc = (idx & 15) * 4;
    u16x4 o;
    o[0] = T[(kc + 0) * 68 + nn];
    o[1] = T[(kc + 1) * 68 + nn];
    o[2] = T[(kc + 2) * 68 + nn];
    o[3] = T[(kc + 3) * 68 + nn];
    *(u16x4*)(Wt + (size_t)(n0 + nn) * 1024 + k0 + kc) = o;
  }
}

// ---------------- qkv = x @ W_attn + biases, BK=64 (R7, measured 70.6us) -----
// 128x128 tile, 4 waves, single 32 KiB LDS buffer, 2 barriers per tile.
// XCD-chunked grid. V-section stores packed 4x2B -> 8B (consecutive t).
// Q pre-scaled by 0.125*log2(e). Q,K stored [B,H,T,D]; V stored [B,H,D,T].
__global__ __launch_bounds__(256) void qkv_gemm(
    const unsigned short* __restrict__ xb, const unsigned short* __restrict__ Wt,
    const float* __restrict__ b_attn, const float* __restrict__ bQ,
    const float* __restrict__ bK, const float* __restrict__ bV,
    unsigned short* __restrict__ Qb, unsigned short* __restrict__ Kb,
    unsigned short* __restrict__ Vb)
{
  __shared__ unsigned short Al[128 * 64];
  __shared__ unsigned short Bl[128 * 64];
  const int tid = threadIdx.x;
  const int w = tid >> 6, lane = tid & 63;
  const int l16 = lane & 15, quad = lane >> 4;
  const int xcd = blockIdx.x & 7, kk = blockIdx.x >> 3;   // kk 0..191
  const int mblk = xcd * 8 + (kk & 7), nblk = kk >> 3;    // 64 mblk x 24 nblk
  const int m0 = mblk * 128, n0 = nblk * 128;
  const int wm = (w & 1) * 64, wn = (w >> 1) * 64;

  const int srow = lane >> 3;                           // 0..7
  const int schunk = ((lane & 7) ^ (srow & 7)) * 8;     // XOR bank swizzle
  const unsigned short* ga = xb + (size_t)(m0 + w * 8 + srow) * 1024 + schunk;
  const unsigned short* gb = Wt + (size_t)(n0 + w * 8 + srow) * 1024 + schunk;
  unsigned short* la = &Al[(w * 8) * 64];
  unsigned short* lb = &Bl[(w * 8) * 64];

  f32x4 acc[4][4] = {};

  for (int kb = 0; kb < 1024; kb += 64) {
    __syncthreads();
#pragma unroll
    for (int i = 0; i < 4; ++i) {
      g2l16(ga + kb + (size_t)i * 32 * 1024, la + i * 32 * 64);
      g2l16(gb + kb + (size_t)i * 32 * 1024, lb + i * 32 * 64);
    }
    __syncthreads();
    bf16x8 af[4][2], bfr[4][2];
#pragma unroll
    for (int mi = 0; mi < 4; ++mi)
#pragma unroll
      for (int dk = 0; dk < 2; ++dk)
        af[mi][dk] = lds_load8(
            &Al[(wm + mi * 16 + l16) * 64 + (((dk * 4 + quad) ^ (l16 & 7)) * 8)]);
#pragma unroll
    for (int ni = 0; ni < 4; ++ni)
#pragma unroll
      for (int dk = 0; dk < 2; ++dk)
        bfr[ni][dk] = lds_load8(
            &Bl[(wn + ni * 16 + l16) * 64 + (((dk * 4 + quad) ^ (l16 & 7)) * 8)]);
#pragma unroll
    for (int mi = 0; mi < 4; ++mi)
#pragma unroll
      for (int ni = 0; ni < 4; ++ni) {
        acc[mi][ni] = __builtin_amdgcn_mfma_f32_16x16x32_bf16(
            af[mi][0], bfr[ni][0], acc[mi][ni], 0, 0, 0);
        acc[mi][ni] = __builtin_amdgcn_mfma_f32_16x16x32_bf16(
            af[mi][1], bfr[ni][1], acc[mi][ni], 0, 0, 0);
      }
  }

  unsigned short* dst[4];
  float biasv[4], sc[4];
  int st[4];
#pragma unroll
  for (int ni = 0; ni < 4; ++ni) {
    int col = n0 + wn + ni * 16 + l16;
    int sec = col >> 10, cc = col & 1023;
    const float* hb = (sec == 0) ? bQ : (sec == 1 ? bK : bV);
    biasv[ni] = b_attn[col] + hb[cc];
    sc[ni] = (sec == 0) ? 0.125f * 1.44269504f : 1.0f;
    if (sec == 2) {   // V transposed: [h][d][t]
      dst[ni] = Vb + (size_t)(cc >> 6) * (DD * TT) + (size_t)(cc & 63) * TT;
      st[ni] = 1;
    } else {
      unsigned short* base = (sec == 0) ? Qb : Kb;
      dst[ni] = base + (size_t)(cc >> 6) * (TT * DD) + (cc & 63);
      st[ni] = 64;
    }
  }
#pragma unroll
  for (int mi = 0; mi < 4; ++mi) {
    const int mbase = m0 + wm + mi * 16 + quad * 4;   // 4-aligned, no 2048-straddle
#pragma unroll
    for (int ni = 0; ni < 4; ++ni) {
      if (st[ni] == 1) {               // V: 4 consecutive t -> one 8B store
        int bidx = mbase >> 11, t = mbase & 2047;
        size_t co = (size_t)bidx * (HH * TT * DD);
        u16x4 pkt;
#pragma unroll
        for (int r = 0; r < 4; ++r)
          pkt[r] = f2bf(acc[mi][ni][r] + biasv[ni]);   // sc==1 for V
        *(u16x4*)(dst[ni] + co + t) = pkt;
      } else {                          // Q/K: stride-64 scalar stores
#pragma unroll
        for (int r = 0; r < 4; ++r) {
          int m = mbase + r;
          int bidx = m >> 11, t = m & 2047;
          size_t co = (size_t)bidx * (HH * TT * DD);
          dst[ni][co + (size_t)t * 64] = f2bf((acc[mi][ni][r] + biasv[ni]) * sc[ni]);
        }
      }
    }
  }
}

// ---------------- causal flash attention, static-max softmax ----------------
// block = 4 waves x 32 q-rows = 128 rows; BK=64; grid = 16 qt x 64 bh (LPT).
// K double-buffered in LDS; V read DIRECTLY from global (L2-resident via bh%8
// XCD affinity) into B-fragments — the staged read resolved to
// Vg[dn*16+l16][k0+kc*32+quad*8], identical to a direct 16B load, so Vl was
// pure overhead (guide CM#7). LDS 51->34 KB -> 4 blocks/CU target.
// exp via bare v_exp_f32; s_setprio around MFMA clusters; one barrier/tile.
__global__ __launch_bounds__(256) void attn_kernel(
    const unsigned short* __restrict__ Qb, const unsigned short* __restrict__ Kb,
    const unsigned short* __restrict__ Vtg, unsigned short* __restrict__ Yb)
{
  __shared__ unsigned short Kl[2 * 4096];
  __shared__ unsigned short Pl[4 * 32 * 72];
  const int tid = threadIdx.x;
  const int w = tid >> 6, lane = tid & 63;
  const int l16 = lane & 15, quad = lane >> 4;
  const int qt = 15 - (blockIdx.x >> 6);   // longest first (LPT)
  const int bh = blockIdx.x & 63;          // bh%8 fixed per XCD -> K/V L2 locality
  const int b = bh >> 4, h = bh & 15;
  const int q0 = qt * 128, qw = q0 + w * 32;

  const unsigned short* Qg = Qb + (size_t)bh * TT * DD;
  const unsigned short* Kg = Kb + (size_t)bh * TT * DD;
  const unsigned short* Vg = Vtg + (size_t)bh * DD * TT;   // [d][t]

  // Q fragments (pre-scaled by 0.125*log2e)
  bf16x8 qf[2][2];
#pragma unroll
  for (int mi = 0; mi < 2; ++mi)
#pragma unroll
    for (int dk = 0; dk < 2; ++dk) {
      u32x4 t = *(const u32x4*)(Qg + (size_t)(qw + mi * 16 + l16) * 64 + dk * 32 + quad * 8);
      qf[mi][dk] = __builtin_bit_cast(bf16x8, t);
    }

  f32x4 accO[2][4] = {};
  f32x4 accL[2] = {};
  u16x8 o16;
#pragma unroll
  for (int j = 0; j < 8; ++j) o16[j] = 0x3F80;   // bf16 1.0
  const bf16x8 onesf = __builtin_bit_cast(bf16x8, o16);

  // K staging: LDS row = w*8 + lane/8 (and +32), phys chunk = lane%8
  const int srow = w * 8 + (lane >> 3);
  const int schunk = ((lane & 7) ^ (srow & 7)) * 8;       // XOR bank swizzle
  const int kkey = 4 * (srow & 15) + (srow >> 4);          // key permutation
  const unsigned short* gk1 = Kg + (size_t)kkey * 64 + schunk;
  const unsigned short* gk2 = Kg + (size_t)(kkey + 2) * 64 + schunk;

  // V direct-load base: lane (l16,quad) reads row d = dn*16+l16, col quad*8
  const unsigned short* vbase = Vg + (size_t)l16 * TT + quad * 8;

  const int kend = q0 + 64;   // waves 2,3 need one tile past q0

  // prologue: stage K tile 0 into slot 0
  g2l16(gk1, &Kl[w * 512]);
  g2l16(gk2, &Kl[w * 512 + 2048]);
  __syncthreads();

  int cur = 0;
  for (int k0 = 0; k0 <= kend; k0 += 64) {
    // stage next K tile into the other slot (issued early; lands under compute)
    const int nxt = (cur ^ 1) * 4096;
    if (k0 + 64 <= kend) {
      g2l16(gk1 + (size_t)(k0 + 64) * 64, &Kl[nxt + w * 512]);
      g2l16(gk2 + (size_t)(k0 + 64) * 64, &Kl[nxt + w * 512 + 2048]);
    }
    if (k0 <= qw + 31) {
      const int co = cur * 4096;

      // V fragments direct from global (issued early; QK+softmax hides L2 lat)
      u32x4 vr[2][4];
#pragma unroll
      for (int kc = 0; kc < 2; ++kc)
#pragma unroll
        for (int dn = 0; dn < 4; ++dn)
          vr[kc][dn] = *(const u32x4*)(vbase + (size_t)(dn * 16) * TT + k0 + kc * 32);

      // S = Q K^T
      f32x4 accS[2][4] = {};
      __builtin_amdgcn_s_setprio(1);
#pragma unroll
      for (int ni = 0; ni < 4; ++ni)
#pragma unroll
        for (int dk = 0; dk < 2; ++dk) {
          bf16x8 kf = lds_load8(
              &Kl[co + (ni * 16 + l16) * 64 + (((dk * 4 + quad) ^ (l16 & 7)) * 8)]);
#pragma unroll
          for (int mi = 0; mi < 2; ++mi)
            accS[mi][ni] = __builtin_amdgcn_mfma_f32_16x16x32_bf16(
                qf[mi][dk], kf, accS[mi][ni], 0, 0, 0);
        }
      __builtin_amdgcn_s_setprio(0);

      // static-max softmax: p = exp2(s); accS[ni] col l16 <-> key k0 + 4*l16 + ni
      const bool maskT = (k0 + 63 > qw);
#pragma unroll
      for (int mi = 0; mi < 2; ++mi)
#pragma unroll
        for (int r = 0; r < 4; ++r) {
          int qrow = qw + mi * 16 + quad * 4 + r;
          float s0 = accS[mi][0][r], s1 = accS[mi][1][r];
          float s2 = accS[mi][2][r], s3 = accS[mi][3][r];
          if (maskT) {
            int kb = k0 + 4 * l16;
            if (kb + 0 > qrow) s0 = -3e38f;
            if (kb + 1 > qrow) s1 = -3e38f;
            if (kb + 2 > qrow) s2 = -3e38f;
            if (kb + 3 > qrow) s3 = -3e38f;
          }
          u32 e0 = __builtin_bit_cast(u32, exp2_raw(s0));
          u32 e1 = __builtin_bit_cast(u32, exp2_raw(s1));
          u32 e2 = __builtin_bit_cast(u32, exp2_raw(s2));
          u32 e3 = __builtin_bit_cast(u32, exp2_raw(s3));
          u32x2 pv;
          pv[0] = __builtin_amdgcn_perm(e1, e0, 0x07060302);  // [hi16(e0),hi16(e1)]
          pv[1] = __builtin_amdgcn_perm(e3, e2, 0x07060302);
          *(u32x2*)(&Pl[(w * 32 + mi * 16 + quad * 4 + r) * 72 + 4 * l16]) = pv;
        }

      // O += P V ; L += P . ones   (Pl per-wave, no barrier)
      __builtin_amdgcn_s_setprio(1);
#pragma unroll
      for (int kc = 0; kc < 2; ++kc) {
        bf16x8 pf[2];
#pragma unroll
        for (int mi = 0; mi < 2; ++mi)
          pf[mi] = lds_load8(&Pl[(w * 32 + mi * 16 + l16) * 72 + kc * 32 + quad * 8]);
#pragma unroll
        for (int dn = 0; dn < 4; ++dn) {
          bf16x8 vf = __builtin_bit_cast(bf16x8, vr[kc][dn]);
#pragma unroll
          for (int mi = 0; mi < 2; ++mi)
            accO[mi][dn] = __builtin_amdgcn_mfma_f32_16x16x32_bf16(
                pf[mi], vf, accO[mi][dn], 0, 0, 0);
        }
#pragma unroll
        for (int mi = 0; mi < 2; ++mi)
          accL[mi] = __builtin_amdgcn_mfma_f32_16x16x32_bf16(
              pf[mi], onesf, accL[mi], 0, 0, 0);
      }
      __builtin_amdgcn_s_setprio(0);
    }
    __syncthreads();   // all reads of K slot cur done; next iter overwrites it
    cur ^= 1;
  }

#pragma unroll
  for (int mi = 0; mi < 2; ++mi)
#pragma unroll
    for (int r = 0; r < 4; ++r) {
      int q = qw + mi * 16 + quad * 4 + r;
      float inv = 1.0f / accL[mi][r];
      size_t base = ((size_t)b * TT + q) * CC + h * DD;
#pragma unroll
      for (int dn = 0; dn < 4; ++dn)
        Yb[base + dn * 16 + l16] = f2bf(accO[mi][dn][r] * inv);
    }
}

// ---------------- out = y @ W_proj + b_proj (fp32 out), BK=64 (R7) -----------
__global__ __launch_bounds__(256) void proj_gemm(
    const unsigned short* __restrict__ Yb, const unsigned short* __restrict__ Wt,
    const float* __restrict__ bp, float* __restrict__ out)
{
  __shared__ unsigned short Al[128 * 64];
  __shared__ unsigned short Bl[128 * 64];
  const int tid = threadIdx.x;
  const int w = tid >> 6, lane = tid & 63;
  const int l16 = lane & 15, quad = lane >> 4;
  const int xcd = blockIdx.x & 7, kk = blockIdx.x >> 3;   // kk 0..63
  const int mblk = xcd * 8 + (kk & 7), nblk = kk >> 3;    // 64 mblk x 8 nblk
  const int m0 = mblk * 128, n0 = nblk * 128;
  const int wm = (w & 1) * 64, wn = (w >> 1) * 64;

  const int srow = lane >> 3;
  const int schunk = ((lane & 7) ^ (srow & 7)) * 8;
  const unsigned short* ga = Yb + (size_t)(m0 + w * 8 + srow) * 1024 + schunk;
  const unsigned short* gb = Wt + (size_t)(n0 + w * 8 + srow) * 1024 + schunk;
  unsigned short* la = &Al[(w * 8) * 64];
  unsigned short* lb = &Bl[(w * 8) * 64];

  f32x4 acc[4][4] = {};

  for (int kb = 0; kb < 1024; kb += 64) {
    __syncthreads();
#pragma unroll
    for (int i = 0; i < 4; ++i) {
      g2l16(ga + kb + (size_t)i * 32 * 1024, la + i * 32 * 64);
      g2l16(gb + kb + (size_t)i * 32 * 1024, lb + i * 32 * 64);
    }
    __syncthreads();
    bf16x8 af[4][2], bfr[4][2];
#pragma unroll
    for (int mi = 0; mi < 4; ++mi)
#pragma unroll
      for (int dk = 0; dk < 2; ++dk)
        af[mi][dk] = lds_load8(
            &Al[(wm + mi * 16 + l16) * 64 + (((dk * 4 + quad) ^ (l16 & 7)) * 8)]);
#pragma unroll
    for (int ni = 0; ni < 4; ++ni)
#pragma unroll
      for (int dk = 0; dk < 2; ++dk)
        bfr[ni][dk] = lds_load8(
            &Bl[(wn + ni * 16 + l16) * 64 + (((dk * 4 + quad) ^ (l16 & 7)) * 8)]);
#pragma unroll
    for (int mi = 0; mi < 4; ++mi)
#pragma unroll
      for (int ni = 0; ni < 4; ++ni) {
        acc[mi][ni] = __builtin_amdgcn_mfma_f32_16x16x32_bf16(
            af[mi][0], bfr[ni][0], acc[mi][ni], 0, 0, 0);
        acc[mi][ni] = __builtin_amdgcn_mfma_f32_16x16x32_bf16(
            af[mi][1], bfr[ni][1], acc[mi][ni], 0, 0, 0);
      }
  }

#pragma unroll
  for (int mi = 0; mi < 4; ++mi)
#pragma unroll
    for (int r = 0; r < 4; ++r) {
      int m = m0 + wm + mi * 16 + quad * 4 + r;
#pragma unroll
      for (int ni = 0; ni < 4; ++ni) {
        int c = n0 + wn + ni * 16 + l16;
        out[(size_t)m * 1024 + c] = acc[mi][ni][r] + bp[c];
      }
    }
}

extern "C" void kernel_launch(void* const* d_in, const int* in_sizes, int n_in,
                              void* d_out, int out_size, void* d_ws, size_t ws_size,
                              hipStream_t stream) {
  const float* x      = (const float*)d_in[0];
  const float* W_attn = (const float*)d_in[1];
  const float* b_attn = (const float*)d_in[2];
  const float* W_proj = (const float*)d_in[3];
  const float* b_proj = (const float*)d_in[4];
  const float* bQ     = (const float*)d_in[5];
  const float* bK     = (const float*)d_in[6];
  const float* bV     = (const float*)d_in[7];
  float* out = (float*)d_out;

  unsigned short* xb   = (unsigned short*)d_ws;        // 8,388,608
  unsigned short* Yb   = xb;                           // alias (xb dead after qkv)
  unsigned short* Wt_a = xb + 8388608;                 // 3,145,728
  unsigned short* Wt_p = Wt_a + 3145728;               // 1,048,576
  unsigned short* Qb   = Wt_p + 1048576;               // 8,388,608
  unsigned short* Kb   = Qb + 8388608;
  unsigned short* Vb   = Kb + 8388608;                 // [B,H,D,T]

  prep<<<dim3(4096 + 768 + 256), dim3(256), 0, stream>>>(x, W_attn, W_proj,
                                                         xb, Wt_a, Wt_p);
  qkv_gemm<<<dim3(64 * 24), dim3(256), 0, stream>>>(xb, Wt_a, b_attn, bQ, bK, bV,
                                                    Qb, Kb, Vb);
  attn_kernel<<<dim3(16 * 64), dim3(256), 0, stream>>>(Qb, Kb, Vb, Yb);
  proj_gemm<<<dim3(64 * 8), dim3(256), 0, stream>>>(Yb, Wt_p, b_proj, out);
}

// Round 10
// 255.100 us; speedup vs baseline: 1.0711x; 1.0711x over previous
//
#include <hip/hip_runtime.h>
#include <hip/hip_bf16.h>

#define BB 4
#define TT 2048
#define CC 1024
#define HH 16
#define DD 64

typedef __bf16 bf16x8 __attribute__((ext_vector_type(8)));
typedef float f32x4 __attribute__((ext_vector_type(4)));
typedef unsigned int u32x4 __attribute__((ext_vector_type(4)));
typedef unsigned int u32x2 __attribute__((ext_vector_type(2)));
typedef unsigned short u16x8 __attribute__((ext_vector_type(8)));
typedef unsigned short u16x4 __attribute__((ext_vector_type(4)));
typedef unsigned int u32;

__device__ __forceinline__ unsigned short f2bf(float f) {
  u32 u = __builtin_bit_cast(u32, f);
  u += 0x7fff + ((u >> 16) & 1);   // RNE
  return (unsigned short)(u >> 16);
}

// bare v_exp_f32: skips the IEEE-denormal fixup sequence hipcc emits for
// exp2f. Inputs are normal scores or -3e38 (exp->0). 1 VALU.
__device__ __forceinline__ float exp2_raw(float x) {
  float r;
  asm("v_exp_f32 %0, %1" : "=v"(r) : "v"(x));
  return r;
}

__device__ __forceinline__ bf16x8 lds_load8(const unsigned short* p) {
  u32x4 t = *(const u32x4*)p;
  return __builtin_bit_cast(bf16x8, t);
}

// async 16B global->LDS (dest = wave-uniform base + lane*16)
__device__ __forceinline__ void g2l16(const unsigned short* g, unsigned short* l) {
  __builtin_amdgcn_global_load_lds(
      (const __attribute__((address_space(1))) u32*)g,
      (__attribute__((address_space(3))) u32*)l, 16, 0, 0);
}

// ---------------- fused prep: xcast + W_attn^T + W_proj^T ----------------
__global__ __launch_bounds__(256) void prep(
    const float* __restrict__ x, const float* __restrict__ Wa,
    const float* __restrict__ Wp, unsigned short* __restrict__ xb,
    unsigned short* __restrict__ Wta, unsigned short* __restrict__ Wtp)
{
  __shared__ unsigned short T[64 * 68];
  const int tid = threadIdx.x;
  const int bid = blockIdx.x;
  if (bid < 4096) {                       // x fp32 -> bf16
    int i = (bid * 256 + tid) * 8;
    f32x4 a = *(const f32x4*)(x + i);
    f32x4 b = *(const f32x4*)(x + i + 4);
    u16x8 o;
    o[0] = f2bf(a[0]); o[1] = f2bf(a[1]); o[2] = f2bf(a[2]); o[3] = f2bf(a[3]);
    o[4] = f2bf(b[0]); o[5] = f2bf(b[1]); o[6] = f2bf(b[2]); o[7] = f2bf(b[3]);
    *(u16x8*)(xb + i) = o;
    return;
  }
  const float* W; unsigned short* Wt; int N, n0, k0;
  if (bid < 4096 + 768) {
    int b2 = bid - 4096;  W = Wa; Wt = Wta; N = 3072;
    n0 = (b2 % 48) * 64;  k0 = (b2 / 48) * 64;
  } else {
    int b2 = bid - 4864;  W = Wp; Wt = Wtp; N = 1024;
    n0 = (b2 % 16) * 64;  k0 = (b2 / 16) * 64;
  }
#pragma unroll
  for (int it = 0; it < 4; ++it) {
    int idx = it * 256 + tid;
    int kk = idx >> 4, nn = (idx & 15) * 4;
    f32x4 v = *(const f32x4*)(W + (size_t)(k0 + kk) * N + n0 + nn);
    u16x4 p;
    p[0] = f2bf(v[0]); p[1] = f2bf(v[1]); p[2] = f2bf(v[2]); p[3] = f2bf(v[3]);
    *(u16x4*)(&T[kk * 68 + nn]) = p;
  }
  __syncthreads();
#pragma unroll
  for (int it = 0; it < 4; ++it) {
    int idx = it * 256 + tid;
    int nn = idx >> 4, kc = (idx & 15) * 4;
    u16x4 o;
    o[0] = T[(kc + 0) * 68 + nn];
    o[1] = T[(kc + 1) * 68 + nn];
    o[2] = T[(kc + 2) * 68 + nn];
    o[3] = T[(kc + 3) * 68 + nn];
    *(u16x4*)(Wt + (size_t)(n0 + nn) * 1024 + k0 + kc) = o;
  }
}

// ---------------- qkv = x @ W_attn + biases, BK=64 (R7, measured 70.6us) -----
// 128x128 tile, 4 waves, single 32 KiB LDS buffer, 2 barriers per tile.
// XCD-chunked grid. V-section stores packed 4x2B -> 8B (consecutive t).
// Q pre-scaled by 0.125*log2(e). Q,K stored [B,H,T,D]; V stored [B,H,D,T].
__global__ __launch_bounds__(256) void qkv_gemm(
    const unsigned short* __restrict__ xb, const unsigned short* __restrict__ Wt,
    const float* __restrict__ b_attn, const float* __restrict__ bQ,
    const float* __restrict__ bK, const float* __restrict__ bV,
    unsigned short* __restrict__ Qb, unsigned short* __restrict__ Kb,
    unsigned short* __restrict__ Vb)
{
  __shared__ unsigned short Al[128 * 64];
  __shared__ unsigned short Bl[128 * 64];
  const int tid = threadIdx.x;
  const int w = tid >> 6, lane = tid & 63;
  const int l16 = lane & 15, quad = lane >> 4;
  const int xcd = blockIdx.x & 7, kk = blockIdx.x >> 3;   // kk 0..191
  const int mblk = xcd * 8 + (kk & 7), nblk = kk >> 3;    // 64 mblk x 24 nblk
  const int m0 = mblk * 128, n0 = nblk * 128;
  const int wm = (w & 1) * 64, wn = (w >> 1) * 64;

  const int srow = lane >> 3;                           // 0..7
  const int schunk = ((lane & 7) ^ (srow & 7)) * 8;     // XOR bank swizzle
  const unsigned short* ga = xb + (size_t)(m0 + w * 8 + srow) * 1024 + schunk;
  const unsigned short* gb = Wt + (size_t)(n0 + w * 8 + srow) * 1024 + schunk;
  unsigned short* la = &Al[(w * 8) * 64];
  unsigned short* lb = &Bl[(w * 8) * 64];

  f32x4 acc[4][4] = {};

  for (int kb = 0; kb < 1024; kb += 64) {
    __syncthreads();
#pragma unroll
    for (int i = 0; i < 4; ++i) {
      g2l16(ga + kb + (size_t)i * 32 * 1024, la + i * 32 * 64);
      g2l16(gb + kb + (size_t)i * 32 * 1024, lb + i * 32 * 64);
    }
    __syncthreads();
    bf16x8 af[4][2], bfr[4][2];
#pragma unroll
    for (int mi = 0; mi < 4; ++mi)
#pragma unroll
      for (int dk = 0; dk < 2; ++dk)
        af[mi][dk] = lds_load8(
            &Al[(wm + mi * 16 + l16) * 64 + (((dk * 4 + quad) ^ (l16 & 7)) * 8)]);
#pragma unroll
    for (int ni = 0; ni < 4; ++ni)
#pragma unroll
      for (int dk = 0; dk < 2; ++dk)
        bfr[ni][dk] = lds_load8(
            &Bl[(wn + ni * 16 + l16) * 64 + (((dk * 4 + quad) ^ (l16 & 7)) * 8)]);
#pragma unroll
    for (int mi = 0; mi < 4; ++mi)
#pragma unroll
      for (int ni = 0; ni < 4; ++ni) {
        acc[mi][ni] = __builtin_amdgcn_mfma_f32_16x16x32_bf16(
            af[mi][0], bfr[ni][0], acc[mi][ni], 0, 0, 0);
        acc[mi][ni] = __builtin_amdgcn_mfma_f32_16x16x32_bf16(
            af[mi][1], bfr[ni][1], acc[mi][ni], 0, 0, 0);
      }
  }

  unsigned short* dst[4];
  float biasv[4], sc[4];
  int st[4];
#pragma unroll
  for (int ni = 0; ni < 4; ++ni) {
    int col = n0 + wn + ni * 16 + l16;
    int sec = col >> 10, cc = col & 1023;
    const float* hb = (sec == 0) ? bQ : (sec == 1 ? bK : bV);
    biasv[ni] = b_attn[col] + hb[cc];
    sc[ni] = (sec == 0) ? 0.125f * 1.44269504f : 1.0f;
    if (sec == 2) {   // V transposed: [h][d][t]
      dst[ni] = Vb + (size_t)(cc >> 6) * (DD * TT) + (size_t)(cc & 63) * TT;
      st[ni] = 1;
    } else {
      unsigned short* base = (sec == 0) ? Qb : Kb;
      dst[ni] = base + (size_t)(cc >> 6) * (TT * DD) + (cc & 63);
      st[ni] = 64;
    }
  }
#pragma unroll
  for (int mi = 0; mi < 4; ++mi) {
    const int mbase = m0 + wm + mi * 16 + quad * 4;   // 4-aligned, no 2048-straddle
#pragma unroll
    for (int ni = 0; ni < 4; ++ni) {
      if (st[ni] == 1) {               // V: 4 consecutive t -> one 8B store
        int bidx = mbase >> 11, t = mbase & 2047;
        size_t co = (size_t)bidx * (HH * TT * DD);
        u16x4 pkt;
#pragma unroll
        for (int r = 0; r < 4; ++r)
          pkt[r] = f2bf(acc[mi][ni][r] + biasv[ni]);   // sc==1 for V
        *(u16x4*)(dst[ni] + co + t) = pkt;
      } else {                          // Q/K: stride-64 scalar stores
#pragma unroll
        for (int r = 0; r < 4; ++r) {
          int m = mbase + r;
          int bidx = m >> 11, t = m & 2047;
          size_t co = (size_t)bidx * (HH * TT * DD);
          dst[ni][co + (size_t)t * 64] = f2bf((acc[mi][ni][r] + biasv[ni]) * sc[ni]);
        }
      }
    }
  }
}

// ---------------- causal flash attention, static-max softmax ----------------
// block = 4 waves x 32 q-rows = 128 rows; BK=64; grid = 16 qt x 64 bh (LPT).
// K/V double-buffered (2x8 KiB each), stage t+1 issued at loop top,
// ONE barrier per tile; s_setprio(1) around MFMA clusters.
// exp via bare v_exp_f32 (exp2_raw). [Measured-best structure: R6's
// 64-row/wave cost a resident block (latency-bound); R9's V-direct-from-
// global drained the K prefetch via the shared vmcnt counter. Keep this.]
__global__ __launch_bounds__(256) void attn_kernel(
    const unsigned short* __restrict__ Qb, const unsigned short* __restrict__ Kb,
    const unsigned short* __restrict__ Vtg, unsigned short* __restrict__ Yb)
{
  __shared__ unsigned short Kl[2 * 4096];
  __shared__ unsigned short Vl[2 * 4096];
  __shared__ unsigned short Pl[4 * 32 * 72];
  const int tid = threadIdx.x;
  const int w = tid >> 6, lane = tid & 63;
  const int l16 = lane & 15, quad = lane >> 4;
  const int qt = 15 - (blockIdx.x >> 6);   // longest first (LPT)
  const int bh = blockIdx.x & 63;          // bh%8 fixed per XCD -> K/V L2 locality
  const int b = bh >> 4, h = bh & 15;
  const int q0 = qt * 128, qw = q0 + w * 32;

  const unsigned short* Qg = Qb + (size_t)bh * TT * DD;
  const unsigned short* Kg = Kb + (size_t)bh * TT * DD;
  const unsigned short* Vg = Vtg + (size_t)bh * DD * TT;   // [d][t]

  // Q fragments (pre-scaled by 0.125*log2e)
  bf16x8 qf[2][2];
#pragma unroll
  for (int mi = 0; mi < 2; ++mi)
#pragma unroll
    for (int dk = 0; dk < 2; ++dk) {
      u32x4 t = *(const u32x4*)(Qg + (size_t)(qw + mi * 16 + l16) * 64 + dk * 32 + quad * 8);
      qf[mi][dk] = __builtin_bit_cast(bf16x8, t);
    }

  f32x4 accO[2][4] = {};
  f32x4 accL[2] = {};
  u16x8 o16;
#pragma unroll
  for (int j = 0; j < 8; ++j) o16[j] = 0x3F80;   // bf16 1.0
  const bf16x8 onesf = __builtin_bit_cast(bf16x8, o16);

  // staging: LDS row = w*8 + lane/8 (and +32), phys chunk = lane%8
  const int srow = w * 8 + (lane >> 3);
  const int schunk = ((lane & 7) ^ (srow & 7)) * 8;       // XOR bank swizzle
  const int kkey = 4 * (srow & 15) + (srow >> 4);          // key permutation
  const unsigned short* gk1 = Kg + (size_t)kkey * 64 + schunk;
  const unsigned short* gk2 = Kg + (size_t)(kkey + 2) * 64 + schunk;
  const unsigned short* gv1 = Vg + (size_t)srow * TT + schunk;
  const unsigned short* gv2 = Vg + (size_t)(srow + 32) * TT + schunk;

  const int kend = q0 + 64;   // waves 2,3 need one tile past q0

  // prologue: stage tile 0 into slot 0
  g2l16(gk1, &Kl[w * 512]);
  g2l16(gk2, &Kl[w * 512 + 2048]);
  g2l16(gv1, &Vl[w * 512]);
  g2l16(gv2, &Vl[w * 512 + 2048]);
  __syncthreads();

  int cur = 0;
  for (int k0 = 0; k0 <= kend; k0 += 64) {
    // stage next tile into the other slot (issued early; lands under compute)
    const int nxt = (cur ^ 1) * 4096;
    if (k0 + 64 <= kend) {
      g2l16(gk1 + (size_t)(k0 + 64) * 64, &Kl[nxt + w * 512]);
      g2l16(gk2 + (size_t)(k0 + 64) * 64, &Kl[nxt + w * 512 + 2048]);
      g2l16(gv1 + (k0 + 64), &Vl[nxt + w * 512]);
      g2l16(gv2 + (k0 + 64), &Vl[nxt + w * 512 + 2048]);
    }
    if (k0 <= qw + 31) {
      const int co = cur * 4096;

      // S = Q K^T
      f32x4 accS[2][4] = {};
      __builtin_amdgcn_s_setprio(1);
#pragma unroll
      for (int ni = 0; ni < 4; ++ni)
#pragma unroll
        for (int dk = 0; dk < 2; ++dk) {
          bf16x8 kf = lds_load8(
              &Kl[co + (ni * 16 + l16) * 64 + (((dk * 4 + quad) ^ (l16 & 7)) * 8)]);
#pragma unroll
          for (int mi = 0; mi < 2; ++mi)
            accS[mi][ni] = __builtin_amdgcn_mfma_f32_16x16x32_bf16(
                qf[mi][dk], kf, accS[mi][ni], 0, 0, 0);
        }
      __builtin_amdgcn_s_setprio(0);

      // static-max softmax: p = exp2(s); accS[ni] col l16 <-> key k0 + 4*l16 + ni
      const bool maskT = (k0 + 63 > qw);
#pragma unroll
      for (int mi = 0; mi < 2; ++mi)
#pragma unroll
        for (int r = 0; r < 4; ++r) {
          int qrow = qw + mi * 16 + quad * 4 + r;
          float s0 = accS[mi][0][r], s1 = accS[mi][1][r];
          float s2 = accS[mi][2][r], s3 = accS[mi][3][r];
          if (maskT) {
            int kb = k0 + 4 * l16;
            if (kb + 0 > qrow) s0 = -3e38f;
            if (kb + 1 > qrow) s1 = -3e38f;
            if (kb + 2 > qrow) s2 = -3e38f;
            if (kb + 3 > qrow) s3 = -3e38f;
          }
          u32 e0 = __builtin_bit_cast(u32, exp2_raw(s0));
          u32 e1 = __builtin_bit_cast(u32, exp2_raw(s1));
          u32 e2 = __builtin_bit_cast(u32, exp2_raw(s2));
          u32 e3 = __builtin_bit_cast(u32, exp2_raw(s3));
          u32x2 pv;
          pv[0] = __builtin_amdgcn_perm(e1, e0, 0x07060302);  // [hi16(e0),hi16(e1)]
          pv[1] = __builtin_amdgcn_perm(e3, e2, 0x07060302);
          *(u32x2*)(&Pl[(w * 32 + mi * 16 + quad * 4 + r) * 72 + 4 * l16]) = pv;
        }

      // O += P V ; L += P . ones   (Pl per-wave, no barrier)
      __builtin_amdgcn_s_setprio(1);
#pragma unroll
      for (int kc = 0; kc < 2; ++kc) {
        bf16x8 pf[2];
#pragma unroll
        for (int mi = 0; mi < 2; ++mi)
          pf[mi] = lds_load8(&Pl[(w * 32 + mi * 16 + l16) * 72 + kc * 32 + quad * 8]);
#pragma unroll
        for (int dn = 0; dn < 4; ++dn) {
          bf16x8 vf = lds_load8(
              &Vl[co + (dn * 16 + l16) * 64 + (((kc * 4 + quad) ^ (l16 & 7)) * 8)]);
#pragma unroll
          for (int mi = 0; mi < 2; ++mi)
            accO[mi][dn] = __builtin_amdgcn_mfma_f32_16x16x32_bf16(
                pf[mi], vf, accO[mi][dn], 0, 0, 0);
        }
#pragma unroll
        for (int mi = 0; mi < 2; ++mi)
          accL[mi] = __builtin_amdgcn_mfma_f32_16x16x32_bf16(
              pf[mi], onesf, accL[mi], 0, 0, 0);
      }
      __builtin_amdgcn_s_setprio(0);
    }
    __syncthreads();   // all reads of slot cur done; next iter overwrites it
    cur ^= 1;
  }

#pragma unroll
  for (int mi = 0; mi < 2; ++mi)
#pragma unroll
    for (int r = 0; r < 4; ++r) {
      int q = qw + mi * 16 + quad * 4 + r;
      float inv = 1.0f / accL[mi][r];
      size_t base = ((size_t)b * TT + q) * CC + h * DD;
#pragma unroll
      for (int dn = 0; dn < 4; ++dn)
        Yb[base + dn * 16 + l16] = f2bf(accO[mi][dn][r] * inv);
    }
}

// ---------------- out = y @ W_proj + b_proj (fp32 out), BK=64 ----------------
__global__ __launch_bounds__(256) void proj_gemm(
    const unsigned short* __restrict__ Yb, const unsigned short* __restrict__ Wt,
    const float* __restrict__ bp, float* __restrict__ out)
{
  __shared__ unsigned short Al[128 * 64];
  __shared__ unsigned short Bl[128 * 64];
  const int tid = threadIdx.x;
  const int w = tid >> 6, lane = tid & 63;
  const int l16 = lane & 15, quad = lane >> 4;
  const int xcd = blockIdx.x & 7, kk = blockIdx.x >> 3;   // kk 0..63
  const int mblk = xcd * 8 + (kk & 7), nblk = kk >> 3;    // 64 mblk x 8 nblk
  const int m0 = mblk * 128, n0 = nblk * 128;
  const int wm = (w & 1) * 64, wn = (w >> 1) * 64;

  const int srow = lane >> 3;
  const int schunk = ((lane & 7) ^ (srow & 7)) * 8;
  const unsigned short* ga = Yb + (size_t)(m0 + w * 8 + srow) * 1024 + schunk;
  const unsigned short* gb = Wt + (size_t)(n0 + w * 8 + srow) * 1024 + schunk;
  unsigned short* la = &Al[(w * 8) * 64];
  unsigned short* lb = &Bl[(w * 8) * 64];

  f32x4 acc[4][4] = {};

  for (int kb = 0; kb < 1024; kb += 64) {
    __syncthreads();
#pragma unroll
    for (int i = 0; i < 4; ++i) {
      g2l16(ga + kb + (size_t)i * 32 * 1024, la + i * 32 * 64);
      g2l16(gb + kb + (size_t)i * 32 * 1024, lb + i * 32 * 64);
    }
    __syncthreads();
    bf16x8 af[4][2], bfr[4][2];
#pragma unroll
    for (int mi = 0; mi < 4; ++mi)
#pragma unroll
      for (int dk = 0; dk < 2; ++dk)
        af[mi][dk] = lds_load8(
            &Al[(wm + mi * 16 + l16) * 64 + (((dk * 4 + quad) ^ (l16 & 7)) * 8)]);
#pragma unroll
    for (int ni = 0; ni < 4; ++ni)
#pragma unroll
      for (int dk = 0; dk < 2; ++dk)
        bfr[ni][dk] = lds_load8(
            &Bl[(wn + ni * 16 + l16) * 64 + (((dk * 4 + quad) ^ (l16 & 7)) * 8)]);
#pragma unroll
    for (int mi = 0; mi < 4; ++mi)
#pragma unroll
      for (int ni = 0; ni < 4; ++ni) {
        acc[mi][ni] = __builtin_amdgcn_mfma_f32_16x16x32_bf16(
            af[mi][0], bfr[ni][0], acc[mi][ni], 0, 0, 0);
        acc[mi][ni] = __builtin_amdgcn_mfma_f32_16x16x32_bf16(
            af[mi][1], bfr[ni][1], acc[mi][ni], 0, 0, 0);
      }
  }

#pragma unroll
  for (int mi = 0; mi < 4; ++mi)
#pragma unroll
    for (int r = 0; r < 4; ++r) {
      int m = m0 + wm + mi * 16 + quad * 4 + r;
#pragma unroll
      for (int ni = 0; ni < 4; ++ni) {
        int c = n0 + wn + ni * 16 + l16;
        out[(size_t)m * 1024 + c] = acc[mi][ni][r] + bp[c];
      }
    }
}

extern "C" void kernel_launch(void* const* d_in, const int* in_sizes, int n_in,
                              void* d_out, int out_size, void* d_ws, size_t ws_size,
                              hipStream_t stream) {
  const float* x      = (const float*)d_in[0];
  const float* W_attn = (const float*)d_in[1];
  const float* b_attn = (const float*)d_in[2];
  const float* W_proj = (const float*)d_in[3];
  const float* b_proj = (const float*)d_in[4];
  const float* bQ     = (const float*)d_in[5];
  const float* bK     = (const float*)d_in[6];
  const float* bV     = (const float*)d_in[7];
  float* out = (float*)d_out;

  unsigned short* xb   = (unsigned short*)d_ws;        // 8,388,608
  unsigned short* Yb   = xb;                           // alias (xb dead after qkv)
  unsigned short* Wt_a = xb + 8388608;                 // 3,145,728
  unsigned short* Wt_p = Wt_a + 3145728;               // 1,048,576
  unsigned short* Qb   = Wt_p + 1048576;               // 8,388,608
  unsigned short* Kb   = Qb + 8388608;
  unsigned short* Vb   = Kb + 8388608;                 // [B,H,D,T]

  prep<<<dim3(4096 + 768 + 256), dim3(256), 0, stream>>>(x, W_attn, W_proj,
                                                         xb, Wt_a, Wt_p);
  qkv_gemm<<<dim3(64 * 24), dim3(256), 0, stream>>>(xb, Wt_a, b_attn, bQ, bK, bV,
                                                    Qb, Kb, Vb);
  attn_kernel<<<dim3(16 * 64), dim3(256), 0, stream>>>(Qb, Kb, Vb, Yb);
  proj_gemm<<<dim3(64 * 8), dim3(256), 0, stream>>>(Yb, Wt_p, b_proj, out);
}

// Round 11
// 247.536 us; speedup vs baseline: 1.1038x; 1.0306x over previous
//
#include <hip/hip_runtime.h>
#include <hip/hip_bf16.h>

#define BB 4
#define TT 2048
#define CC 1024
#define HH 16
#define DD 64

typedef __bf16 bf16x8 __attribute__((ext_vector_type(8)));
typedef float f32x4 __attribute__((ext_vector_type(4)));
typedef unsigned int u32x4 __attribute__((ext_vector_type(4)));
typedef unsigned int u32x2 __attribute__((ext_vector_type(2)));
typedef unsigned short u16x8 __attribute__((ext_vector_type(8)));
typedef unsigned short u16x4 __attribute__((ext_vector_type(4)));
typedef unsigned int u32;

__device__ __forceinline__ unsigned short f2bf(float f) {
  u32 u = __builtin_bit_cast(u32, f);
  u += 0x7fff + ((u >> 16) & 1);   // RNE
  return (unsigned short)(u >> 16);
}

// bare v_exp_f32: skips the IEEE-denormal fixup sequence hipcc emits for
// exp2f. Inputs are normal scores or -3e38 (exp->0). 1 VALU.
__device__ __forceinline__ float exp2_raw(float x) {
  float r;
  asm("v_exp_f32 %0, %1" : "=v"(r) : "v"(x));
  return r;
}

__device__ __forceinline__ bf16x8 lds_load8(const unsigned short* p) {
  u32x4 t = *(const u32x4*)p;
  return __builtin_bit_cast(bf16x8, t);
}

// async 16B global->LDS (dest = wave-uniform base + lane*16)
__device__ __forceinline__ void g2l16(const unsigned short* g, unsigned short* l) {
  __builtin_amdgcn_global_load_lds(
      (const __attribute__((address_space(1))) u32*)g,
      (__attribute__((address_space(3))) u32*)l, 16, 0, 0);
}

// ---------------- fused prep: xcast + W_attn^T + W_proj^T ----------------
__global__ __launch_bounds__(256) void prep(
    const float* __restrict__ x, const float* __restrict__ Wa,
    const float* __restrict__ Wp, unsigned short* __restrict__ xb,
    unsigned short* __restrict__ Wta, unsigned short* __restrict__ Wtp)
{
  __shared__ unsigned short T[64 * 68];
  const int tid = threadIdx.x;
  const int bid = blockIdx.x;
  if (bid < 4096) {                       // x fp32 -> bf16
    int i = (bid * 256 + tid) * 8;
    f32x4 a = *(const f32x4*)(x + i);
    f32x4 b = *(const f32x4*)(x + i + 4);
    u16x8 o;
    o[0] = f2bf(a[0]); o[1] = f2bf(a[1]); o[2] = f2bf(a[2]); o[3] = f2bf(a[3]);
    o[4] = f2bf(b[0]); o[5] = f2bf(b[1]); o[6] = f2bf(b[2]); o[7] = f2bf(b[3]);
    *(u16x8*)(xb + i) = o;
    return;
  }
  const float* W; unsigned short* Wt; int N, n0, k0;
  if (bid < 4096 + 768) {
    int b2 = bid - 4096;  W = Wa; Wt = Wta; N = 3072;
    n0 = (b2 % 48) * 64;  k0 = (b2 / 48) * 64;
  } else {
    int b2 = bid - 4864;  W = Wp; Wt = Wtp; N = 1024;
    n0 = (b2 % 16) * 64;  k0 = (b2 / 16) * 64;
  }
#pragma unroll
  for (int it = 0; it < 4; ++it) {
    int idx = it * 256 + tid;
    int kk = idx >> 4, nn = (idx & 15) * 4;
    f32x4 v = *(const f32x4*)(W + (size_t)(k0 + kk) * N + n0 + nn);
    u16x4 p;
    p[0] = f2bf(v[0]); p[1] = f2bf(v[1]); p[2] = f2bf(v[2]); p[3] = f2bf(v[3]);
    *(u16x4*)(&T[kk * 68 + nn]) = p;
  }
  __syncthreads();
#pragma unroll
  for (int it = 0; it < 4; ++it) {
    int idx = it * 256 + tid;
    int nn = idx >> 4, kc = (idx & 15) * 4;
    u16x4 o;
    o[0] = T[(kc + 0) * 68 + nn];
    o[1] = T[(kc + 1) * 68 + nn];
    o[2] = T[(kc + 2) * 68 + nn];
    o[3] = T[(kc + 3) * 68 + nn];
    *(u16x4*)(Wt + (size_t)(n0 + nn) * 1024 + k0 + kc) = o;
  }
}

// ---------------- qkv = x @ W_attn + biases, BK=64 (R7 loop) -----------------
// 128x128 tile, 4 waves, single 32 KiB LDS buffer, 2 barriers per tile.
// XCD-chunked grid. Epilogue:
//   V blocks: 4 consecutive t packed -> one 8B store (R7, measured +10us).
//   Q/K blocks: NEW — LDS-transpose epilogue (loop untouched): 2 passes of
//     64 rows through the dead staging LDS ([64][136] bf16, ~2-way conflicts
//     = free), then 16 packed 8B stores/thread with 4x128B segments
//     (was 64 scalar 2B stores). Store-instruction count is the proven lever
//     (R7); R8's operand-swap failed via loop perturbation, not packing.
// Q pre-scaled by 0.125*log2(e). Q,K stored [B,H,T,D]; V stored [B,H,D,T].
__global__ __launch_bounds__(256) void qkv_gemm(
    const unsigned short* __restrict__ xb, const unsigned short* __restrict__ Wt,
    const float* __restrict__ b_attn, const float* __restrict__ bQ,
    const float* __restrict__ bK, const float* __restrict__ bV,
    unsigned short* __restrict__ Qb, unsigned short* __restrict__ Kb,
    unsigned short* __restrict__ Vb)
{
  __shared__ unsigned short S[16384];   // loop: A=S[0..8191], B=S[8192..]; epi: scratch
  const int tid = threadIdx.x;
  const int w = tid >> 6, lane = tid & 63;
  const int l16 = lane & 15, quad = lane >> 4;
  const int xcd = blockIdx.x & 7, kk = blockIdx.x >> 3;   // kk 0..191
  const int mblk = xcd * 8 + (kk & 7), nblk = kk >> 3;    // 64 mblk x 24 nblk
  const int m0 = mblk * 128, n0 = nblk * 128;
  const int wm = (w & 1) * 64, wn = (w >> 1) * 64;

  const int srow = lane >> 3;                           // 0..7
  const int schunk = ((lane & 7) ^ (srow & 7)) * 8;     // XOR bank swizzle
  const unsigned short* ga = xb + (size_t)(m0 + w * 8 + srow) * 1024 + schunk;
  const unsigned short* gb = Wt + (size_t)(n0 + w * 8 + srow) * 1024 + schunk;
  unsigned short* la = &S[(w * 8) * 64];
  unsigned short* lb = &S[8192 + (w * 8) * 64];

  f32x4 acc[4][4] = {};

  for (int kb = 0; kb < 1024; kb += 64) {
    __syncthreads();
#pragma unroll
    for (int i = 0; i < 4; ++i) {
      g2l16(ga + kb + (size_t)i * 32 * 1024, la + i * 32 * 64);
      g2l16(gb + kb + (size_t)i * 32 * 1024, lb + i * 32 * 64);
    }
    __syncthreads();
    bf16x8 af[4][2], bfr[4][2];
#pragma unroll
    for (int mi = 0; mi < 4; ++mi)
#pragma unroll
      for (int dk = 0; dk < 2; ++dk)
        af[mi][dk] = lds_load8(
            &S[(wm + mi * 16 + l16) * 64 + (((dk * 4 + quad) ^ (l16 & 7)) * 8)]);
#pragma unroll
    for (int ni = 0; ni < 4; ++ni)
#pragma unroll
      for (int dk = 0; dk < 2; ++dk)
        bfr[ni][dk] = lds_load8(
            &S[8192 + (wn + ni * 16 + l16) * 64 + (((dk * 4 + quad) ^ (l16 & 7)) * 8)]);
#pragma unroll
    for (int mi = 0; mi < 4; ++mi)
#pragma unroll
      for (int ni = 0; ni < 4; ++ni) {
        acc[mi][ni] = __builtin_amdgcn_mfma_f32_16x16x32_bf16(
            af[mi][0], bfr[ni][0], acc[mi][ni], 0, 0, 0);
        acc[mi][ni] = __builtin_amdgcn_mfma_f32_16x16x32_bf16(
            af[mi][1], bfr[ni][1], acc[mi][ni], 0, 0, 0);
      }
  }

  if (nblk >= 16) {
    // ---- V blocks (R7 path): acc cols consecutive t after transpose layout
    float biasv[4];
    unsigned short* dst[4];
#pragma unroll
    for (int ni = 0; ni < 4; ++ni) {
      int col = n0 + wn + ni * 16 + l16;
      int cc = col & 1023;
      biasv[ni] = b_attn[col] + bV[cc];
      dst[ni] = Vb + (size_t)(cc >> 6) * (DD * TT) + (size_t)(cc & 63) * TT;
    }
#pragma unroll
    for (int mi = 0; mi < 4; ++mi) {
      const int mbase = m0 + wm + mi * 16 + quad * 4;   // no 2048-straddle
      int bidx = mbase >> 11, t = mbase & 2047;
      size_t co = (size_t)bidx * (HH * TT * DD);
#pragma unroll
      for (int ni = 0; ni < 4; ++ni) {
        u16x4 pkt;
#pragma unroll
        for (int r = 0; r < 4; ++r)
          pkt[r] = f2bf(acc[mi][ni][r] + biasv[ni]);
        *(u16x4*)(dst[ni] + co + t) = pkt;
      }
    }
  } else {
    // ---- Q/K blocks: LDS-transpose epilogue, 2 passes of 64 rows
    const float scq = (nblk < 8) ? 0.125f * 1.44269504f : 1.0f;
    unsigned short* gbase = (nblk < 8) ? Qb : Kb;
    const float* hb = (nblk < 8) ? bQ : bK;
    float biasv[4];
#pragma unroll
    for (int ni = 0; ni < 4; ++ni) {
      int col = n0 + wn + ni * 16 + l16;
      biasv[ni] = b_attn[col] + hb[col & 1023];
    }
#pragma unroll
    for (int p = 0; p < 2; ++p) {
      __syncthreads();               // p=0: staging LDS dead; p=1: prev reads done
      if ((w & 1) == p) {            // waves owning rows [p*64, p*64+64)
#pragma unroll
        for (int mi = 0; mi < 4; ++mi)
#pragma unroll
          for (int ni = 0; ni < 4; ++ni)
#pragma unroll
            for (int r = 0; r < 4; ++r) {
              int row = mi * 16 + quad * 4 + r;         // 0..63
              int col = wn + ni * 16 + l16;             // 0..127
              S[row * 136 + col] = f2bf((acc[mi][ni][r] + biasv[ni]) * scq);
            }
      }
      __syncthreads();
#pragma unroll
      for (int i = 0; i < 8; ++i) {   // all 256 threads: 64x128 -> global
        int fid = i * 256 + tid;
        int row = fid >> 5, col0 = (fid & 31) * 4;
        u16x4 v = *(const u16x4*)&S[row * 136 + col0];
        int cc0 = (n0 + col0) & 1023;                   // head*64 + d0
        int m = m0 + p * 64 + row;
        int bidx = m >> 11, t = m & 2047;
        *(u16x4*)(gbase + (size_t)bidx * (HH * TT * DD)
                  + (size_t)(cc0 >> 6) * (TT * DD) + (size_t)t * 64 + (cc0 & 63)) = v;
      }
    }
  }
}

// ---------------- causal flash attention, static-max softmax ----------------
// block = 4 waves x 32 q-rows = 128 rows; BK=64; grid = 16 qt x 64 bh (LPT).
// K/V double-buffered (2x8 KiB each), stage t+1 issued at loop top,
// ONE barrier per tile; s_setprio(1) around MFMA clusters.
// exp via bare v_exp_f32 (exp2_raw). [Measured-best structure: R6's
// 64-row/wave cost a resident block (latency-bound); R9's V-direct-from-
// global drained the K prefetch via the shared vmcnt counter. Keep this.]
__global__ __launch_bounds__(256) void attn_kernel(
    const unsigned short* __restrict__ Qb, const unsigned short* __restrict__ Kb,
    const unsigned short* __restrict__ Vtg, unsigned short* __restrict__ Yb)
{
  __shared__ unsigned short Kl[2 * 4096];
  __shared__ unsigned short Vl[2 * 4096];
  __shared__ unsigned short Pl[4 * 32 * 72];
  const int tid = threadIdx.x;
  const int w = tid >> 6, lane = tid & 63;
  const int l16 = lane & 15, quad = lane >> 4;
  const int qt = 15 - (blockIdx.x >> 6);   // longest first (LPT)
  const int bh = blockIdx.x & 63;          // bh%8 fixed per XCD -> K/V L2 locality
  const int b = bh >> 4, h = bh & 15;
  const int q0 = qt * 128, qw = q0 + w * 32;

  const unsigned short* Qg = Qb + (size_t)bh * TT * DD;
  const unsigned short* Kg = Kb + (size_t)bh * TT * DD;
  const unsigned short* Vg = Vtg + (size_t)bh * DD * TT;   // [d][t]

  // Q fragments (pre-scaled by 0.125*log2e)
  bf16x8 qf[2][2];
#pragma unroll
  for (int mi = 0; mi < 2; ++mi)
#pragma unroll
    for (int dk = 0; dk < 2; ++dk) {
      u32x4 t = *(const u32x4*)(Qg + (size_t)(qw + mi * 16 + l16) * 64 + dk * 32 + quad * 8);
      qf[mi][dk] = __builtin_bit_cast(bf16x8, t);
    }

  f32x4 accO[2][4] = {};
  f32x4 accL[2] = {};
  u16x8 o16;
#pragma unroll
  for (int j = 0; j < 8; ++j) o16[j] = 0x3F80;   // bf16 1.0
  const bf16x8 onesf = __builtin_bit_cast(bf16x8, o16);

  // staging: LDS row = w*8 + lane/8 (and +32), phys chunk = lane%8
  const int srow = w * 8 + (lane >> 3);
  const int schunk = ((lane & 7) ^ (srow & 7)) * 8;       // XOR bank swizzle
  const int kkey = 4 * (srow & 15) + (srow >> 4);          // key permutation
  const unsigned short* gk1 = Kg + (size_t)kkey * 64 + schunk;
  const unsigned short* gk2 = Kg + (size_t)(kkey + 2) * 64 + schunk;
  const unsigned short* gv1 = Vg + (size_t)srow * TT + schunk;
  const unsigned short* gv2 = Vg + (size_t)(srow + 32) * TT + schunk;

  const int kend = q0 + 64;   // waves 2,3 need one tile past q0

  // prologue: stage tile 0 into slot 0
  g2l16(gk1, &Kl[w * 512]);
  g2l16(gk2, &Kl[w * 512 + 2048]);
  g2l16(gv1, &Vl[w * 512]);
  g2l16(gv2, &Vl[w * 512 + 2048]);
  __syncthreads();

  int cur = 0;
  for (int k0 = 0; k0 <= kend; k0 += 64) {
    // stage next tile into the other slot (issued early; lands under compute)
    const int nxt = (cur ^ 1) * 4096;
    if (k0 + 64 <= kend) {
      g2l16(gk1 + (size_t)(k0 + 64) * 64, &Kl[nxt + w * 512]);
      g2l16(gk2 + (size_t)(k0 + 64) * 64, &Kl[nxt + w * 512 + 2048]);
      g2l16(gv1 + (k0 + 64), &Vl[nxt + w * 512]);
      g2l16(gv2 + (k0 + 64), &Vl[nxt + w * 512 + 2048]);
    }
    if (k0 <= qw + 31) {
      const int co = cur * 4096;

      // S = Q K^T
      f32x4 accS[2][4] = {};
      __builtin_amdgcn_s_setprio(1);
#pragma unroll
      for (int ni = 0; ni < 4; ++ni)
#pragma unroll
        for (int dk = 0; dk < 2; ++dk) {
          bf16x8 kf = lds_load8(
              &Kl[co + (ni * 16 + l16) * 64 + (((dk * 4 + quad) ^ (l16 & 7)) * 8)]);
#pragma unroll
          for (int mi = 0; mi < 2; ++mi)
            accS[mi][ni] = __builtin_amdgcn_mfma_f32_16x16x32_bf16(
                qf[mi][dk], kf, accS[mi][ni], 0, 0, 0);
        }
      __builtin_amdgcn_s_setprio(0);

      // static-max softmax: p = exp2(s); accS[ni] col l16 <-> key k0 + 4*l16 + ni
      const bool maskT = (k0 + 63 > qw);
#pragma unroll
      for (int mi = 0; mi < 2; ++mi)
#pragma unroll
        for (int r = 0; r < 4; ++r) {
          int qrow = qw + mi * 16 + quad * 4 + r;
          float s0 = accS[mi][0][r], s1 = accS[mi][1][r];
          float s2 = accS[mi][2][r], s3 = accS[mi][3][r];
          if (maskT) {
            int kb = k0 + 4 * l16;
            if (kb + 0 > qrow) s0 = -3e38f;
            if (kb + 1 > qrow) s1 = -3e38f;
            if (kb + 2 > qrow) s2 = -3e38f;
            if (kb + 3 > qrow) s3 = -3e38f;
          }
          u32 e0 = __builtin_bit_cast(u32, exp2_raw(s0));
          u32 e1 = __builtin_bit_cast(u32, exp2_raw(s1));
          u32 e2 = __builtin_bit_cast(u32, exp2_raw(s2));
          u32 e3 = __builtin_bit_cast(u32, exp2_raw(s3));
          u32x2 pv;
          pv[0] = __builtin_amdgcn_perm(e1, e0, 0x07060302);  // [hi16(e0),hi16(e1)]
          pv[1] = __builtin_amdgcn_perm(e3, e2, 0x07060302);
          *(u32x2*)(&Pl[(w * 32 + mi * 16 + quad * 4 + r) * 72 + 4 * l16]) = pv;
        }

      // O += P V ; L += P . ones   (Pl per-wave, no barrier)
      __builtin_amdgcn_s_setprio(1);
#pragma unroll
      for (int kc = 0; kc < 2; ++kc) {
        bf16x8 pf[2];
#pragma unroll
        for (int mi = 0; mi < 2; ++mi)
          pf[mi] = lds_load8(&Pl[(w * 32 + mi * 16 + l16) * 72 + kc * 32 + quad * 8]);
#pragma unroll
        for (int dn = 0; dn < 4; ++dn) {
          bf16x8 vf = lds_load8(
              &Vl[co + (dn * 16 + l16) * 64 + (((kc * 4 + quad) ^ (l16 & 7)) * 8)]);
#pragma unroll
          for (int mi = 0; mi < 2; ++mi)
            accO[mi][dn] = __builtin_amdgcn_mfma_f32_16x16x32_bf16(
                pf[mi], vf, accO[mi][dn], 0, 0, 0);
        }
#pragma unroll
        for (int mi = 0; mi < 2; ++mi)
          accL[mi] = __builtin_amdgcn_mfma_f32_16x16x32_bf16(
              pf[mi], onesf, accL[mi], 0, 0, 0);
      }
      __builtin_amdgcn_s_setprio(0);
    }
    __syncthreads();   // all reads of slot cur done; next iter overwrites it
    cur ^= 1;
  }

#pragma unroll
  for (int mi = 0; mi < 2; ++mi)
#pragma unroll
    for (int r = 0; r < 4; ++r) {
      int q = qw + mi * 16 + quad * 4 + r;
      float inv = 1.0f / accL[mi][r];
      size_t base = ((size_t)b * TT + q) * CC + h * DD;
#pragma unroll
      for (int dn = 0; dn < 4; ++dn)
        Yb[base + dn * 16 + l16] = f2bf(accO[mi][dn][r] * inv);
    }
}

// ---------------- out = y @ W_proj + b_proj (fp32 out), BK=64 ----------------
__global__ __launch_bounds__(256) void proj_gemm(
    const unsigned short* __restrict__ Yb, const unsigned short* __restrict__ Wt,
    const float* __restrict__ bp, float* __restrict__ out)
{
  __shared__ unsigned short Al[128 * 64];
  __shared__ unsigned short Bl[128 * 64];
  const int tid = threadIdx.x;
  const int w = tid >> 6, lane = tid & 63;
  const int l16 = lane & 15, quad = lane >> 4;
  const int xcd = blockIdx.x & 7, kk = blockIdx.x >> 3;   // kk 0..63
  const int mblk = xcd * 8 + (kk & 7), nblk = kk >> 3;    // 64 mblk x 8 nblk
  const int m0 = mblk * 128, n0 = nblk * 128;
  const int wm = (w & 1) * 64, wn = (w >> 1) * 64;

  const int srow = lane >> 3;
  const int schunk = ((lane & 7) ^ (srow & 7)) * 8;
  const unsigned short* ga = Yb + (size_t)(m0 + w * 8 + srow) * 1024 + schunk;
  const unsigned short* gb = Wt + (size_t)(n0 + w * 8 + srow) * 1024 + schunk;
  unsigned short* la = &Al[(w * 8) * 64];
  unsigned short* lb = &Bl[(w * 8) * 64];

  f32x4 acc[4][4] = {};

  for (int kb = 0; kb < 1024; kb += 64) {
    __syncthreads();
#pragma unroll
    for (int i = 0; i < 4; ++i) {
      g2l16(ga + kb + (size_t)i * 32 * 1024, la + i * 32 * 64);
      g2l16(gb + kb + (size_t)i * 32 * 1024, lb + i * 32 * 64);
    }
    __syncthreads();
    bf16x8 af[4][2], bfr[4][2];
#pragma unroll
    for (int mi = 0; mi < 4; ++mi)
#pragma unroll
      for (int dk = 0; dk < 2; ++dk)
        af[mi][dk] = lds_load8(
            &Al[(wm + mi * 16 + l16) * 64 + (((dk * 4 + quad) ^ (l16 & 7)) * 8)]);
#pragma unroll
    for (int ni = 0; ni < 4; ++ni)
#pragma unroll
      for (int dk = 0; dk < 2; ++dk)
        bfr[ni][dk] = lds_load8(
            &Bl[(wn + ni * 16 + l16) * 64 + (((dk * 4 + quad) ^ (l16 & 7)) * 8)]);
#pragma unroll
    for (int mi = 0; mi < 4; ++mi)
#pragma unroll
      for (int ni = 0; ni < 4; ++ni) {
        acc[mi][ni] = __builtin_amdgcn_mfma_f32_16x16x32_bf16(
            af[mi][0], bfr[ni][0], acc[mi][ni], 0, 0, 0);
        acc[mi][ni] = __builtin_amdgcn_mfma_f32_16x16x32_bf16(
            af[mi][1], bfr[ni][1], acc[mi][ni], 0, 0, 0);
      }
  }

#pragma unroll
  for (int mi = 0; mi < 4; ++mi)
#pragma unroll
    for (int r = 0; r < 4; ++r) {
      int m = m0 + wm + mi * 16 + quad * 4 + r;
#pragma unroll
      for (int ni = 0; ni < 4; ++ni) {
        int c = n0 + wn + ni * 16 + l16;
        out[(size_t)m * 1024 + c] = acc[mi][ni][r] + bp[c];
      }
    }
}

extern "C" void kernel_launch(void* const* d_in, const int* in_sizes, int n_in,
                              void* d_out, int out_size, void* d_ws, size_t ws_size,
                              hipStream_t stream) {
  const float* x      = (const float*)d_in[0];
  const float* W_attn = (const float*)d_in[1];
  const float* b_attn = (const float*)d_in[2];
  const float* W_proj = (const float*)d_in[3];
  const float* b_proj = (const float*)d_in[4];
  const float* bQ     = (const float*)d_in[5];
  const float* bK     = (const float*)d_in[6];
  const float* bV     = (const float*)d_in[7];
  float* out = (float*)d_out;

  unsigned short* xb   = (unsigned short*)d_ws;        // 8,388,608
  unsigned short* Yb   = xb;                           // alias (xb dead after qkv)
  unsigned short* Wt_a = xb + 8388608;                 // 3,145,728
  unsigned short* Wt_p = Wt_a + 3145728;               // 1,048,576
  unsigned short* Qb   = Wt_p + 1048576;               // 8,388,608
  unsigned short* Kb   = Qb + 8388608;
  unsigned short* Vb   = Kb + 8388608;                 // [B,H,D,T]

  prep<<<dim3(4096 + 768 + 256), dim3(256), 0, stream>>>(x, W_attn, W_proj,
                                                         xb, Wt_a, Wt_p);
  qkv_gemm<<<dim3(64 * 24), dim3(256), 0, stream>>>(xb, Wt_a, b_attn, bQ, bK, bV,
                                                    Qb, Kb, Vb);
  attn_kernel<<<dim3(16 * 64), dim3(256), 0, stream>>>(Qb, Kb, Vb, Yb);
  proj_gemm<<<dim3(64 * 8), dim3(256), 0, stream>>>(Yb, Wt_p, b_proj, out);
}

// Round 12
// 240.815 us; speedup vs baseline: 1.1346x; 1.0279x over previous
//
#include <hip/hip_runtime.h>
#include <hip/hip_bf16.h>

#define BB 4
#define TT 2048
#define CC 1024
#define HH 16
#define DD 64

typedef __bf16 bf16x8 __attribute__((ext_vector_type(8)));
typedef float f32x4 __attribute__((ext_vector_type(4)));
typedef unsigned int u32x4 __attribute__((ext_vector_type(4)));
typedef unsigned int u32x2 __attribute__((ext_vector_type(2)));
typedef unsigned short u16x8 __attribute__((ext_vector_type(8)));
typedef unsigned short u16x4 __attribute__((ext_vector_type(4)));
typedef unsigned int u32;

__device__ __forceinline__ unsigned short f2bf(float f) {
  u32 u = __builtin_bit_cast(u32, f);
  u += 0x7fff + ((u >> 16) & 1);   // RNE
  return (unsigned short)(u >> 16);
}

// bare v_exp_f32: skips the IEEE-denormal fixup sequence hipcc emits for
// exp2f. Inputs are normal scores or -3e38 (exp->0). 1 VALU.
__device__ __forceinline__ float exp2_raw(float x) {
  float r;
  asm("v_exp_f32 %0, %1" : "=v"(r) : "v"(x));
  return r;
}

__device__ __forceinline__ bf16x8 lds_load8(const unsigned short* p) {
  u32x4 t = *(const u32x4*)p;
  return __builtin_bit_cast(bf16x8, t);
}

// async 16B global->LDS (dest = wave-uniform base + lane*16)
__device__ __forceinline__ void g2l16(const unsigned short* g, unsigned short* l) {
  __builtin_amdgcn_global_load_lds(
      (const __attribute__((address_space(1))) u32*)g,
      (__attribute__((address_space(3))) u32*)l, 16, 0, 0);
}

// ---------------- fused prep: xcast + W_attn^T + W_proj^T ----------------
__global__ __launch_bounds__(256) void prep(
    const float* __restrict__ x, const float* __restrict__ Wa,
    const float* __restrict__ Wp, unsigned short* __restrict__ xb,
    unsigned short* __restrict__ Wta, unsigned short* __restrict__ Wtp)
{
  __shared__ unsigned short T[64 * 68];
  const int tid = threadIdx.x;
  const int bid = blockIdx.x;
  if (bid < 4096) {                       // x fp32 -> bf16
    int i = (bid * 256 + tid) * 8;
    f32x4 a = *(const f32x4*)(x + i);
    f32x4 b = *(const f32x4*)(x + i + 4);
    u16x8 o;
    o[0] = f2bf(a[0]); o[1] = f2bf(a[1]); o[2] = f2bf(a[2]); o[3] = f2bf(a[3]);
    o[4] = f2bf(b[0]); o[5] = f2bf(b[1]); o[6] = f2bf(b[2]); o[7] = f2bf(b[3]);
    *(u16x8*)(xb + i) = o;
    return;
  }
  const float* W; unsigned short* Wt; int N, n0, k0;
  if (bid < 4096 + 768) {
    int b2 = bid - 4096;  W = Wa; Wt = Wta; N = 3072;
    n0 = (b2 % 48) * 64;  k0 = (b2 / 48) * 64;
  } else {
    int b2 = bid - 4864;  W = Wp; Wt = Wtp; N = 1024;
    n0 = (b2 % 16) * 64;  k0 = (b2 / 16) * 64;
  }
#pragma unroll
  for (int it = 0; it < 4; ++it) {
    int idx = it * 256 + tid;
    int kk = idx >> 4, nn = (idx & 15) * 4;
    f32x4 v = *(const f32x4*)(W + (size_t)(k0 + kk) * N + n0 + nn);
    u16x4 p;
    p[0] = f2bf(v[0]); p[1] = f2bf(v[1]); p[2] = f2bf(v[2]); p[3] = f2bf(v[3]);
    *(u16x4*)(&T[kk * 68 + nn]) = p;
  }
  __syncthreads();
#pragma unroll
  for (int it = 0; it < 4; ++it) {
    int idx = it * 256 + tid;
    int nn = idx >> 4, kc = (idx & 15) * 4;
    u16x4 o;
    o[0] = T[(kc + 0) * 68 + nn];
    o[1] = T[(kc + 1) * 68 + nn];
    o[2] = T[(kc + 2) * 68 + nn];
    o[3] = T[(kc + 3) * 68 + nn];
    *(u16x4*)(Wt + (size_t)(n0 + nn) * 1024 + k0 + kc) = o;
  }
}

// ---------------- qkv = x @ W_attn + biases, BK=64 (R11, measured 69.4us) ----
// 128x128 tile, 4 waves, single 32 KiB LDS buffer, 2 barriers per tile.
// XCD-chunked grid. V: packed 8B stores; Q/K: LDS-transpose epilogue.
// Q pre-scaled by 0.125*log2(e). Q,K stored [B,H,T,D]; V stored [B,H,D,T].
__global__ __launch_bounds__(256) void qkv_gemm(
    const unsigned short* __restrict__ xb, const unsigned short* __restrict__ Wt,
    const float* __restrict__ b_attn, const float* __restrict__ bQ,
    const float* __restrict__ bK, const float* __restrict__ bV,
    unsigned short* __restrict__ Qb, unsigned short* __restrict__ Kb,
    unsigned short* __restrict__ Vb)
{
  __shared__ unsigned short S[16384];   // loop: A=S[0..8191], B=S[8192..]; epi: scratch
  const int tid = threadIdx.x;
  const int w = tid >> 6, lane = tid & 63;
  const int l16 = lane & 15, quad = lane >> 4;
  const int xcd = blockIdx.x & 7, kk = blockIdx.x >> 3;   // kk 0..191
  const int mblk = xcd * 8 + (kk & 7), nblk = kk >> 3;    // 64 mblk x 24 nblk
  const int m0 = mblk * 128, n0 = nblk * 128;
  const int wm = (w & 1) * 64, wn = (w >> 1) * 64;

  const int srow = lane >> 3;                           // 0..7
  const int schunk = ((lane & 7) ^ (srow & 7)) * 8;     // XOR bank swizzle
  const unsigned short* ga = xb + (size_t)(m0 + w * 8 + srow) * 1024 + schunk;
  const unsigned short* gb = Wt + (size_t)(n0 + w * 8 + srow) * 1024 + schunk;
  unsigned short* la = &S[(w * 8) * 64];
  unsigned short* lb = &S[8192 + (w * 8) * 64];

  f32x4 acc[4][4] = {};

  for (int kb = 0; kb < 1024; kb += 64) {
    __syncthreads();
#pragma unroll
    for (int i = 0; i < 4; ++i) {
      g2l16(ga + kb + (size_t)i * 32 * 1024, la + i * 32 * 64);
      g2l16(gb + kb + (size_t)i * 32 * 1024, lb + i * 32 * 64);
    }
    __syncthreads();
    bf16x8 af[4][2], bfr[4][2];
#pragma unroll
    for (int mi = 0; mi < 4; ++mi)
#pragma unroll
      for (int dk = 0; dk < 2; ++dk)
        af[mi][dk] = lds_load8(
            &S[(wm + mi * 16 + l16) * 64 + (((dk * 4 + quad) ^ (l16 & 7)) * 8)]);
#pragma unroll
    for (int ni = 0; ni < 4; ++ni)
#pragma unroll
      for (int dk = 0; dk < 2; ++dk)
        bfr[ni][dk] = lds_load8(
            &S[8192 + (wn + ni * 16 + l16) * 64 + (((dk * 4 + quad) ^ (l16 & 7)) * 8)]);
#pragma unroll
    for (int mi = 0; mi < 4; ++mi)
#pragma unroll
      for (int ni = 0; ni < 4; ++ni) {
        acc[mi][ni] = __builtin_amdgcn_mfma_f32_16x16x32_bf16(
            af[mi][0], bfr[ni][0], acc[mi][ni], 0, 0, 0);
        acc[mi][ni] = __builtin_amdgcn_mfma_f32_16x16x32_bf16(
            af[mi][1], bfr[ni][1], acc[mi][ni], 0, 0, 0);
      }
  }

  if (nblk >= 16) {
    // ---- V blocks (R7 path): 4 consecutive t -> one 8B store
    float biasv[4];
    unsigned short* dst[4];
#pragma unroll
    for (int ni = 0; ni < 4; ++ni) {
      int col = n0 + wn + ni * 16 + l16;
      int cc = col & 1023;
      biasv[ni] = b_attn[col] + bV[cc];
      dst[ni] = Vb + (size_t)(cc >> 6) * (DD * TT) + (size_t)(cc & 63) * TT;
    }
#pragma unroll
    for (int mi = 0; mi < 4; ++mi) {
      const int mbase = m0 + wm + mi * 16 + quad * 4;   // no 2048-straddle
      int bidx = mbase >> 11, t = mbase & 2047;
      size_t co = (size_t)bidx * (HH * TT * DD);
#pragma unroll
      for (int ni = 0; ni < 4; ++ni) {
        u16x4 pkt;
#pragma unroll
        for (int r = 0; r < 4; ++r)
          pkt[r] = f2bf(acc[mi][ni][r] + biasv[ni]);
        *(u16x4*)(dst[ni] + co + t) = pkt;
      }
    }
  } else {
    // ---- Q/K blocks: LDS-transpose epilogue, 2 passes of 64 rows
    const float scq = (nblk < 8) ? 0.125f * 1.44269504f : 1.0f;
    unsigned short* gbase = (nblk < 8) ? Qb : Kb;
    const float* hb = (nblk < 8) ? bQ : bK;
    float biasv[4];
#pragma unroll
    for (int ni = 0; ni < 4; ++ni) {
      int col = n0 + wn + ni * 16 + l16;
      biasv[ni] = b_attn[col] + hb[col & 1023];
    }
#pragma unroll
    for (int p = 0; p < 2; ++p) {
      __syncthreads();               // p=0: staging LDS dead; p=1: prev reads done
      if ((w & 1) == p) {            // waves owning rows [p*64, p*64+64)
#pragma unroll
        for (int mi = 0; mi < 4; ++mi)
#pragma unroll
          for (int ni = 0; ni < 4; ++ni)
#pragma unroll
            for (int r = 0; r < 4; ++r) {
              int row = mi * 16 + quad * 4 + r;         // 0..63
              int col = wn + ni * 16 + l16;             // 0..127
              S[row * 136 + col] = f2bf((acc[mi][ni][r] + biasv[ni]) * scq);
            }
      }
      __syncthreads();
#pragma unroll
      for (int i = 0; i < 8; ++i) {   // all 256 threads: 64x128 -> global
        int fid = i * 256 + tid;
        int row = fid >> 5, col0 = (fid & 31) * 4;
        u16x4 v = *(const u16x4*)&S[row * 136 + col0];
        int cc0 = (n0 + col0) & 1023;                   // head*64 + d0
        int m = m0 + p * 64 + row;
        int bidx = m >> 11, t = m & 2047;
        *(u16x4*)(gbase + (size_t)bidx * (HH * TT * DD)
                  + (size_t)(cc0 >> 6) * (TT * DD) + (size_t)t * 64 + (cc0 & 63)) = v;
      }
    }
  }
}

// ---------------- causal flash attention, in-register P (swapped QK^T) ------
// block = 4 waves x 32 q-rows; BK=64; grid = 16 qt x 64 bh (LPT).
// SWAPPED orientation: S^T = mfma(K_frag, Q_frag) puts, for q = l16, the
// tile's keys in lane registers at positions p = 16ni + 4quad + r. K rows
// staged BIT-PERMUTED (key(p) = 32(p>>5) + 8((p>>2)&3) + 4((p>>4)&1) + (p&3),
// bijective) so the packed softmax pairs ARE the PV B-fragment lane-local:
// Pl LDS round-trip eliminated (8 ds_write + 4 ds_read/tile), LDS 50K->32K
// -> 4 blocks/CU. PV: O^T = mfma(V_frag, P_frag); V [d][t] LDS read is
// UNCHANGED as the A operand (A/B frags layout-identical for 16x16x32 —
// in-situ evidence: qkv loads both sides with the same pattern). L via
// ones-MFMA in the A slot (all-ones side-invariant). Y: 8B packed stores
// (d = 16dn + 4quad + rr consecutive). exp2_raw; setprio; one barrier/tile.
__global__ __launch_bounds__(256) void attn_kernel(
    const unsigned short* __restrict__ Qb, const unsigned short* __restrict__ Kb,
    const unsigned short* __restrict__ Vtg, unsigned short* __restrict__ Yb)
{
  __shared__ unsigned short Kl[2 * 4096];
  __shared__ unsigned short Vl[2 * 4096];
  const int tid = threadIdx.x;
  const int w = tid >> 6, lane = tid & 63;
  const int l16 = lane & 15, quad = lane >> 4;
  const int qt = 15 - (blockIdx.x >> 6);   // longest first (LPT)
  const int bh = blockIdx.x & 63;          // bh%8 fixed per XCD -> K/V L2 locality
  const int b = bh >> 4, h = bh & 15;
  const int q0 = qt * 128, qw = q0 + w * 32;

  const unsigned short* Qg = Qb + (size_t)bh * TT * DD;
  const unsigned short* Kg = Kb + (size_t)bh * TT * DD;
  const unsigned short* Vg = Vtg + (size_t)bh * DD * TT;   // [d][t]

  // Q fragments (pre-scaled by 0.125*log2e) — same loads, now the B operand
  bf16x8 qf[2][2];
#pragma unroll
  for (int mi = 0; mi < 2; ++mi)
#pragma unroll
    for (int dk = 0; dk < 2; ++dk) {
      u32x4 t = *(const u32x4*)(Qg + (size_t)(qw + mi * 16 + l16) * 64 + dk * 32 + quad * 8);
      qf[mi][dk] = __builtin_bit_cast(bf16x8, t);
    }

  f32x4 accO[2][4] = {};   // [mi][dn]: rows = d (16dn+4quad+rr), col = q (l16)
  f32x4 accLt[2] = {};     // ones-MFMA L accumulator; all r equal
  u16x8 o16;
#pragma unroll
  for (int j = 0; j < 8; ++j) o16[j] = 0x3F80;   // bf16 1.0
  const bf16x8 onesf = __builtin_bit_cast(bf16x8, o16);

  // staging: LDS row = w*8 + lane/8 (and +32), phys chunk = lane%8.
  // K row permutation: LDS row p holds actual key kkey(p) (bit shuffle).
  const int srow = w * 8 + (lane >> 3);                    // 0..31
  const int schunk = ((lane & 7) ^ (srow & 7)) * 8;        // XOR bank swizzle
  const int kkey = 8 * ((srow >> 2) & 3) + 4 * ((srow >> 4) & 1) + (srow & 3);
  const unsigned short* gk1 = Kg + (size_t)kkey * 64 + schunk;
  const unsigned short* gk2 = Kg + (size_t)(kkey + 32) * 64 + schunk;
  const unsigned short* gv1 = Vg + (size_t)srow * TT + schunk;
  const unsigned short* gv2 = Vg + (size_t)(srow + 32) * TT + schunk;

  const int kend = q0 + 64;   // waves 2,3 need one tile past q0

  // prologue: stage tile 0 into slot 0
  g2l16(gk1, &Kl[w * 512]);
  g2l16(gk2, &Kl[w * 512 + 2048]);
  g2l16(gv1, &Vl[w * 512]);
  g2l16(gv2, &Vl[w * 512 + 2048]);
  __syncthreads();

  int cur = 0;
  for (int k0 = 0; k0 <= kend; k0 += 64) {
    // stage next tile into the other slot (issued early; lands under compute)
    const int nxt = (cur ^ 1) * 4096;
    if (k0 + 64 <= kend) {
      g2l16(gk1 + (size_t)(k0 + 64) * 64, &Kl[nxt + w * 512]);
      g2l16(gk2 + (size_t)(k0 + 64) * 64, &Kl[nxt + w * 512 + 2048]);
      g2l16(gv1 + (k0 + 64), &Vl[nxt + w * 512]);
      g2l16(gv2 + (k0 + 64), &Vl[nxt + w * 512 + 2048]);
    }
    if (k0 <= qw + 31) {
      const int co = cur * 4096;

      // S^T = K Q^T (swapped): rows = key positions, col = q = l16
      f32x4 accS[2][4] = {};
      __builtin_amdgcn_s_setprio(1);
#pragma unroll
      for (int ni = 0; ni < 4; ++ni)
#pragma unroll
        for (int dk = 0; dk < 2; ++dk) {
          bf16x8 kf = lds_load8(
              &Kl[co + (ni * 16 + l16) * 64 + (((dk * 4 + quad) ^ (l16 & 7)) * 8)]);
#pragma unroll
          for (int mi = 0; mi < 2; ++mi)
            accS[mi][ni] = __builtin_amdgcn_mfma_f32_16x16x32_bf16(
                kf, qf[mi][dk], accS[mi][ni], 0, 0, 0);
        }
      __builtin_amdgcn_s_setprio(0);

      // softmax: p = exp2(s); position (ni,quad,r) <-> actual key
      // k0 + 32*(ni>>1) + 8*quad + 4*(ni&1) + r. Packed pairs form the
      // PV B-fragment directly: pb[mi][kc][2h+u] = (p[2u],p[2u+1]) of ni=2kc+h.
      const bool maskT = (k0 + 63 > qw);
      u32 pb[2][2][4];
#pragma unroll
      for (int mi = 0; mi < 2; ++mi) {
        const int q = qw + mi * 16 + l16;
#pragma unroll
        for (int ni = 0; ni < 4; ++ni) {
          float s0 = accS[mi][ni][0], s1 = accS[mi][ni][1];
          float s2 = accS[mi][ni][2], s3 = accS[mi][ni][3];
          if (maskT) {
            const int kb = k0 + 32 * (ni >> 1) + 8 * quad + 4 * (ni & 1);
            if (kb + 0 > q) s0 = -3e38f;
            if (kb + 1 > q) s1 = -3e38f;
            if (kb + 2 > q) s2 = -3e38f;
            if (kb + 3 > q) s3 = -3e38f;
          }
          u32 e0 = __builtin_bit_cast(u32, exp2_raw(s0));
          u32 e1 = __builtin_bit_cast(u32, exp2_raw(s1));
          u32 e2 = __builtin_bit_cast(u32, exp2_raw(s2));
          u32 e3 = __builtin_bit_cast(u32, exp2_raw(s3));
          pb[mi][ni >> 1][2 * (ni & 1) + 0] = __builtin_amdgcn_perm(e1, e0, 0x07060302);
          pb[mi][ni >> 1][2 * (ni & 1) + 1] = __builtin_amdgcn_perm(e3, e2, 0x07060302);
        }
      }

      // O^T += V P ; L += ones . P   (all in-register, no Pl)
      __builtin_amdgcn_s_setprio(1);
#pragma unroll
      for (int kc = 0; kc < 2; ++kc) {
        bf16x8 pf[2];
#pragma unroll
        for (int mi = 0; mi < 2; ++mi) {
          u32x4 t;
          t[0] = pb[mi][kc][0]; t[1] = pb[mi][kc][1];
          t[2] = pb[mi][kc][2]; t[3] = pb[mi][kc][3];
          pf[mi] = __builtin_bit_cast(bf16x8, t);
        }
#pragma unroll
        for (int dn = 0; dn < 4; ++dn) {
          bf16x8 vf = lds_load8(
              &Vl[co + (dn * 16 + l16) * 64 + (((kc * 4 + quad) ^ (l16 & 7)) * 8)]);
#pragma unroll
          for (int mi = 0; mi < 2; ++mi)
            accO[mi][dn] = __builtin_amdgcn_mfma_f32_16x16x32_bf16(
                vf, pf[mi], accO[mi][dn], 0, 0, 0);
        }
#pragma unroll
        for (int mi = 0; mi < 2; ++mi)
          accLt[mi] = __builtin_amdgcn_mfma_f32_16x16x32_bf16(
              onesf, pf[mi], accLt[mi], 0, 0, 0);
      }
      __builtin_amdgcn_s_setprio(0);
    }
    __syncthreads();   // all reads of slot cur done; next iter overwrites it
    cur ^= 1;
  }

  // epilogue: q = l16 per lane; d = 16dn + 4quad + rr -> 8B packed stores
#pragma unroll
  for (int mi = 0; mi < 2; ++mi) {
    const int q = qw + mi * 16 + l16;
    const float inv = 1.0f / accLt[mi][0];
    size_t base = ((size_t)b * TT + q) * CC + h * DD + quad * 4;
#pragma unroll
    for (int dn = 0; dn < 4; ++dn) {
      u16x4 pkt;
#pragma unroll
      for (int rr = 0; rr < 4; ++rr)
        pkt[rr] = f2bf(accO[mi][dn][rr] * inv);
      *(u16x4*)(Yb + base + dn * 16) = pkt;
    }
  }
}

// ---------------- out = y @ W_proj + b_proj (fp32 out), BK=64 ----------------
__global__ __launch_bounds__(256) void proj_gemm(
    const unsigned short* __restrict__ Yb, const unsigned short* __restrict__ Wt,
    const float* __restrict__ bp, float* __restrict__ out)
{
  __shared__ unsigned short Al[128 * 64];
  __shared__ unsigned short Bl[128 * 64];
  const int tid = threadIdx.x;
  const int w = tid >> 6, lane = tid & 63;
  const int l16 = lane & 15, quad = lane >> 4;
  const int xcd = blockIdx.x & 7, kk = blockIdx.x >> 3;   // kk 0..63
  const int mblk = xcd * 8 + (kk & 7), nblk = kk >> 3;    // 64 mblk x 8 nblk
  const int m0 = mblk * 128, n0 = nblk * 128;
  const int wm = (w & 1) * 64, wn = (w >> 1) * 64;

  const int srow = lane >> 3;
  const int schunk = ((lane & 7) ^ (srow & 7)) * 8;
  const unsigned short* ga = Yb + (size_t)(m0 + w * 8 + srow) * 1024 + schunk;
  const unsigned short* gb = Wt + (size_t)(n0 + w * 8 + srow) * 1024 + schunk;
  unsigned short* la = &Al[(w * 8) * 64];
  unsigned short* lb = &Bl[(w * 8) * 64];

  f32x4 acc[4][4] = {};

  for (int kb = 0; kb < 1024; kb += 64) {
    __syncthreads();
#pragma unroll
    for (int i = 0; i < 4; ++i) {
      g2l16(ga + kb + (size_t)i * 32 * 1024, la + i * 32 * 64);
      g2l16(gb + kb + (size_t)i * 32 * 1024, lb + i * 32 * 64);
    }
    __syncthreads();
    bf16x8 af[4][2], bfr[4][2];
#pragma unroll
    for (int mi = 0; mi < 4; ++mi)
#pragma unroll
      for (int dk = 0; dk < 2; ++dk)
        af[mi][dk] = lds_load8(
            &Al[(wm + mi * 16 + l16) * 64 + (((dk * 4 + quad) ^ (l16 & 7)) * 8)]);
#pragma unroll
    for (int ni = 0; ni < 4; ++ni)
#pragma unroll
      for (int dk = 0; dk < 2; ++dk)
        bfr[ni][dk] = lds_load8(
            &Bl[(wn + ni * 16 + l16) * 64 + (((dk * 4 + quad) ^ (l16 & 7)) * 8)]);
#pragma unroll
    for (int mi = 0; mi < 4; ++mi)
#pragma unroll
      for (int ni = 0; ni < 4; ++ni) {
        acc[mi][ni] = __builtin_amdgcn_mfma_f32_16x16x32_bf16(
            af[mi][0], bfr[ni][0], acc[mi][ni], 0, 0, 0);
        acc[mi][ni] = __builtin_amdgcn_mfma_f32_16x16x32_bf16(
            af[mi][1], bfr[ni][1], acc[mi][ni], 0, 0, 0);
      }
  }

#pragma unroll
  for (int mi = 0; mi < 4; ++mi)
#pragma unroll
    for (int r = 0; r < 4; ++r) {
      int m = m0 + wm + mi * 16 + quad * 4 + r;
#pragma unroll
      for (int ni = 0; ni < 4; ++ni) {
        int c = n0 + wn + ni * 16 + l16;
        out[(size_t)m * 1024 + c] = acc[mi][ni][r] + bp[c];
      }
    }
}

extern "C" void kernel_launch(void* const* d_in, const int* in_sizes, int n_in,
                              void* d_out, int out_size, void* d_ws, size_t ws_size,
                              hipStream_t stream) {
  const float* x      = (const float*)d_in[0];
  const float* W_attn = (const float*)d_in[1];
  const float* b_attn = (const float*)d_in[2];
  const float* W_proj = (const float*)d_in[3];
  const float* b_proj = (const float*)d_in[4];
  const float* bQ     = (const float*)d_in[5];
  const float* bK     = (const float*)d_in[6];
  const float* bV     = (const float*)d_in[7];
  float* out = (float*)d_out;

  unsigned short* xb   = (unsigned short*)d_ws;        // 8,388,608
  unsigned short* Yb   = xb;                           // alias (xb dead after qkv)
  unsigned short* Wt_a = xb + 8388608;                 // 3,145,728
  unsigned short* Wt_p = Wt_a + 3145728;               // 1,048,576
  unsigned short* Qb   = Wt_p + 1048576;               // 8,388,608
  unsigned short* Kb   = Qb + 8388608;
  unsigned short* Vb   = Kb + 8388608;                 // [B,H,D,T]

  prep<<<dim3(4096 + 768 + 256), dim3(256), 0, stream>>>(x, W_attn, W_proj,
                                                         xb, Wt_a, Wt_p);
  qkv_gemm<<<dim3(64 * 24), dim3(256), 0, stream>>>(xb, Wt_a, b_attn, bQ, bK, bV,
                                                    Qb, Kb, Vb);
  attn_kernel<<<dim3(16 * 64), dim3(256), 0, stream>>>(Qb, Kb, Vb, Yb);
  proj_gemm<<<dim3(64 * 8), dim3(256), 0, stream>>>(Yb, Wt_p, b_proj, out);
}